// Round 1
// baseline (677.261 us; speedup 1.0000x reference)
//
#include <hip/hip_runtime.h>
#include <cstddef>

#define BB 4
#define CC 512
#define NN 4096
#define PAD 68   // 64 + 4 floats: keeps b128 alignment, breaks power-of-2 bank strides

__device__ __forceinline__ float dot4(float4 a, float4 b) {
    return a.x*b.x + a.y*b.y + a.z*b.z + a.w*b.w;
}

// ---------------- Kernel A: fused projections f,g,h ----------------
// Kd[b][i][d] = sum_c Wf[d][c] x[b][c][i]   (K = f, Q = g, V = h)
__global__ __launch_bounds__(256) void proj_kernel(
    const float* __restrict__ x, const float* __restrict__ Wf,
    const float* __restrict__ Wg, const float* __restrict__ Wh,
    float* __restrict__ Kd, float* __restrict__ Qd, float* __restrict__ Vd)
{
    __shared__ float xs[64][PAD];    // [ii][cc]  (x chunk, transposed)
    __shared__ float ws[192][PAD];   // [m*64+o][cc]
    const int t  = threadIdx.x;
    const int b  = blockIdx.x >> 6;
    const int i0 = (blockIdx.x & 63) << 6;
    const int oq = t >> 4;   // o = oq + 16*oo (interleaved -> 2-way banks)
    const int iq = t & 15;   // i = iq + 16*e  (interleaved)

    float acc[3][4][4];
    #pragma unroll
    for (int m = 0; m < 3; m++)
        #pragma unroll
        for (int a = 0; a < 4; a++)
            #pragma unroll
            for (int e = 0; e < 4; e++) acc[m][a][e] = 0.f;

    for (int c0 = 0; c0 < CC; c0 += 64) {
        __syncthreads();
        #pragma unroll
        for (int rep = 0; rep < 4; rep++) {
            int lin = rep*1024 + t*4;
            int cc = lin >> 6, ii = lin & 63;
            float4 v = *(const float4*)(x + ((size_t)(b*CC + c0 + cc))*NN + i0 + ii);
            xs[ii+0][cc] = v.x; xs[ii+1][cc] = v.y; xs[ii+2][cc] = v.z; xs[ii+3][cc] = v.w;
        }
        #pragma unroll
        for (int rep = 0; rep < 12; rep++) {
            int lin = rep*1024 + t*4;
            int row = lin >> 6, cc = lin & 63;
            const float* wp = (row < 64) ? Wf : ((row < 128) ? Wg : Wh);
            int o = row & 63;
            *(float4*)&ws[row][cc] = *(const float4*)(wp + (size_t)o*CC + c0 + cc);
        }
        __syncthreads();
        #pragma unroll
        for (int m = 0; m < 3; m++) {
            #pragma unroll
            for (int c4 = 0; c4 < 16; c4++) {
                float4 w[4], xv[4];
                #pragma unroll
                for (int oo = 0; oo < 4; oo++)
                    w[oo] = *(const float4*)&ws[m*64 + oq + 16*oo][c4*4];
                #pragma unroll
                for (int e = 0; e < 4; e++)
                    xv[e] = *(const float4*)&xs[iq + 16*e][c4*4];
                #pragma unroll
                for (int oo = 0; oo < 4; oo++)
                    #pragma unroll
                    for (int e = 0; e < 4; e++)
                        acc[m][oo][e] += dot4(w[oo], xv[e]);
            }
        }
    }
    float* Om[3] = {Kd, Qd, Vd};
    #pragma unroll
    for (int m = 0; m < 3; m++)
        #pragma unroll
        for (int oo = 0; oo < 4; oo++)
            #pragma unroll
            for (int e = 0; e < 4; e++)
                Om[m][((size_t)b*NN + i0 + iq + 16*e)*64 + oq + 16*oo] = acc[m][oo][e];
}

// ---------------- Kernel B: flash attention (softmax over keys i) ----------------
// saT[b][j][d] = sum_i softmax_i(Q[j]·K[i]) * V[i][d]
__global__ __launch_bounds__(256) void attn_kernel(
    const float* __restrict__ Kd, const float* __restrict__ Qd,
    const float* __restrict__ Vd, float* __restrict__ saT)
{
    __shared__ float Qs[64][PAD];   // [j][d]
    __shared__ float Ks[64][PAD];   // [i][d]
    __shared__ float Vs[64][PAD];   // [i][d]
    __shared__ float Ps[64][PAD];   // [i][j]
    const int t  = threadIdx.x;
    const int b  = blockIdx.x >> 6;
    const int j0 = (blockIdx.x & 63) << 6;
    const int jq = t >> 4;   // j = jq*4 + a   (blocked: b128 P reads, float4 O stores)
    const int iq = t & 15;   // S: i = iq + 16*e (interleaved) ; PV: d = iq*4 + dd

    #pragma unroll
    for (int rep = 0; rep < 4; rep++) {
        int lin = rep*1024 + t*4;
        int jj = lin >> 6, d = lin & 63;
        *(float4*)&Qs[jj][d] = *(const float4*)(Qd + ((size_t)b*NN + j0 + jj)*64 + d);
    }

    float m_r[4], l_r[4], o_acc[4][4];
    #pragma unroll
    for (int a = 0; a < 4; a++) {
        m_r[a] = -1e30f; l_r[a] = 0.f;
        #pragma unroll
        for (int d2 = 0; d2 < 4; d2++) o_acc[a][d2] = 0.f;
    }

    for (int kt = 0; kt < 64; kt++) {
        const size_t base = ((size_t)b*NN + kt*64)*64;
        __syncthreads();   // prev-tile Ps/Vs/Ks readers done
        #pragma unroll
        for (int rep = 0; rep < 4; rep++) {
            int lin = rep*1024 + t*4;
            int ii = lin >> 6, d = lin & 63;
            *(float4*)&Ks[ii][d] = *(const float4*)(Kd + base + (size_t)ii*64 + d);
            *(float4*)&Vs[ii][d] = *(const float4*)(Vd + base + (size_t)ii*64 + d);
        }
        __syncthreads();

        float s[4][4];   // [a=j-sub][e=i-sub]
        #pragma unroll
        for (int a = 0; a < 4; a++)
            #pragma unroll
            for (int e = 0; e < 4; e++) s[a][e] = 0.f;

        #pragma unroll 4
        for (int d4 = 0; d4 < 16; d4++) {
            float4 q[4], k[4];
            #pragma unroll
            for (int a = 0; a < 4; a++) q[a] = *(const float4*)&Qs[jq*4 + a][d4*4];
            #pragma unroll
            for (int e = 0; e < 4; e++) k[e] = *(const float4*)&Ks[iq + 16*e][d4*4];
            #pragma unroll
            for (int a = 0; a < 4; a++)
                #pragma unroll
                for (int e = 0; e < 4; e++)
                    s[a][e] += dot4(q[a], k[e]);
        }

        // online softmax; the 16 iq-lanes of each jq group hold identical m/l/alpha
        float alpha[4];
        #pragma unroll
        for (int a = 0; a < 4; a++) {
            float mx = fmaxf(fmaxf(s[a][0], s[a][1]), fmaxf(s[a][2], s[a][3]));
            #pragma unroll
            for (int off = 1; off < 16; off <<= 1)
                mx = fmaxf(mx, __shfl_xor(mx, off));
            float mnew = fmaxf(m_r[a], mx);
            alpha[a] = __expf(m_r[a] - mnew);
            float rs = 0.f;
            #pragma unroll
            for (int e = 0; e < 4; e++) { float p = __expf(s[a][e] - mnew); s[a][e] = p; rs += p; }
            #pragma unroll
            for (int off = 1; off < 16; off <<= 1)
                rs += __shfl_xor(rs, off);
            l_r[a] = l_r[a]*alpha[a] + rs;
            m_r[a] = mnew;
        }

        #pragma unroll
        for (int a = 0; a < 4; a++)
            #pragma unroll
            for (int e = 0; e < 4; e++)
                Ps[iq + 16*e][jq*4 + a] = s[a][e];
        __syncthreads();

        #pragma unroll
        for (int a = 0; a < 4; a++)
            #pragma unroll
            for (int d2 = 0; d2 < 4; d2++) o_acc[a][d2] *= alpha[a];

        #pragma unroll 8
        for (int i = 0; i < 64; i++) {
            float4 p4 = *(const float4*)&Ps[i][jq*4];
            float4 v4 = *(const float4*)&Vs[i][iq*4];
            float pa[4] = {p4.x, p4.y, p4.z, p4.w};
            float va[4] = {v4.x, v4.y, v4.z, v4.w};
            #pragma unroll
            for (int a = 0; a < 4; a++)
                #pragma unroll
                for (int d2 = 0; d2 < 4; d2++)
                    o_acc[a][d2] += pa[a]*va[d2];
        }
    }

    #pragma unroll
    for (int a = 0; a < 4; a++) {
        float inv = 1.0f / l_r[a];
        float4 r;
        r.x = o_acc[a][0]*inv; r.y = o_acc[a][1]*inv;
        r.z = o_acc[a][2]*inv; r.w = o_acc[a][3]*inv;
        *(float4*)(saT + ((size_t)b*NN + j0 + jq*4 + a)*64 + iq*4) = r;
    }
}

// ---------------- Kernel C: output projection + residual ----------------
// out2[b][o][j] = sum_d Wv[o][d] saT[b][j][d] ;  out1 = gamma*out2 + x
__global__ __launch_bounds__(256) void outproj_kernel(
    const float* __restrict__ saT, const float* __restrict__ Wv,
    const float* __restrict__ x, const float* __restrict__ gamma,
    float* __restrict__ out1, float* __restrict__ out2)
{
    __shared__ float sas[64][PAD];  // [j][d]
    __shared__ float wvs[64][PAD];  // [o][d]
    const int t  = threadIdx.x;
    const int b  = blockIdx.x >> 6;
    const int j0 = (blockIdx.x & 63) << 6;
    const int oq = t >> 4;   // o = oq + 16*oo (interleaved)
    const int jq = t & 15;   // j = jq + 16*jj (interleaved)
    const float g = gamma[0];

    #pragma unroll
    for (int rep = 0; rep < 4; rep++) {
        int lin = rep*1024 + t*4;
        int jj = lin >> 6, d = lin & 63;
        *(float4*)&sas[jj][d] = *(const float4*)(saT + ((size_t)b*NN + j0 + jj)*64 + d);
    }

    for (int oc = 0; oc < 8; oc++) {
        __syncthreads();
        #pragma unroll
        for (int rep = 0; rep < 4; rep++) {
            int lin = rep*1024 + t*4;
            int oo = lin >> 6, d = lin & 63;
            *(float4*)&wvs[oo][d] = *(const float4*)(Wv + (size_t)(oc*64 + oo)*64 + d);
        }
        __syncthreads();

        float acc[4][4];  // [oo][jj]
        #pragma unroll
        for (int a = 0; a < 4; a++)
            #pragma unroll
            for (int e = 0; e < 4; e++) acc[a][e] = 0.f;

        #pragma unroll 4
        for (int d4 = 0; d4 < 16; d4++) {
            float4 w[4], sv[4];
            #pragma unroll
            for (int oo = 0; oo < 4; oo++)
                w[oo] = *(const float4*)&wvs[oq + 16*oo][d4*4];
            #pragma unroll
            for (int jj = 0; jj < 4; jj++)
                sv[jj] = *(const float4*)&sas[jq + 16*jj][d4*4];
            #pragma unroll
            for (int oo = 0; oo < 4; oo++)
                #pragma unroll
                for (int jj = 0; jj < 4; jj++)
                    acc[oo][jj] += dot4(w[oo], sv[jj]);
        }

        #pragma unroll
        for (int oo = 0; oo < 4; oo++) {
            int o = oc*64 + oq + 16*oo;
            #pragma unroll
            for (int jj = 0; jj < 4; jj++) {
                size_t idx = ((size_t)(b*CC + o))*NN + j0 + jq + 16*jj;
                float sv = acc[oo][jj];
                out2[idx] = sv;
                out1[idx] = g*sv + x[idx];
            }
        }
    }
}

extern "C" void kernel_launch(void* const* d_in, const int* in_sizes, int n_in,
                              void* d_out, int out_size, void* d_ws, size_t ws_size,
                              hipStream_t stream) {
    const float* x     = (const float*)d_in[0];
    const float* Wf    = (const float*)d_in[1];
    const float* Wg    = (const float*)d_in[2];
    const float* Wh    = (const float*)d_in[3];
    const float* Wv    = (const float*)d_in[4];
    const float* gamma = (const float*)d_in[5];

    float* out1 = (float*)d_out;                       // out   [B,C,64,64]
    float* out2 = out1 + (size_t)BB*CC*NN;             // sa    [B,C,64,64]

    float* Kd  = (float*)d_ws;                         // f^T  [B,N,64]
    float* Qd  = Kd + (size_t)BB*NN*64;                // g^T  [B,N,64]
    float* Vd  = Qd + (size_t)BB*NN*64;                // h^T  [B,N,64]
    float* sa  = Vd + (size_t)BB*NN*64;                // sa^T [B,N,64]

    dim3 grid(BB*64), block(256);
    proj_kernel<<<grid, block, 0, stream>>>(x, Wf, Wg, Wh, Kd, Qd, Vd);
    attn_kernel<<<grid, block, 0, stream>>>(Kd, Qd, Vd, sa);
    outproj_kernel<<<grid, block, 0, stream>>>(sa, Wv, x, gamma, out1, out2);
}

// Round 2
// 452.664 us; speedup vs baseline: 1.4962x; 1.4962x over previous
//
#include <hip/hip_runtime.h>
#include <cstddef>

#define BB 4
#define CC 512
#define NN 4096
#define PAD 68   // floats per LDS row (64 + 4)

using short8 = __attribute__((ext_vector_type(8))) short;
using f32x4  = __attribute__((ext_vector_type(4))) float;
using us8    = __attribute__((ext_vector_type(8))) unsigned short;

__device__ __forceinline__ unsigned short f2bf(float x) {
    unsigned int u = __float_as_uint(x);
    u += 0x7fffu + ((u >> 16) & 1u);
    return (unsigned short)(u >> 16);
}
__device__ __forceinline__ float bf2f(unsigned short h) {
    return __uint_as_float(((unsigned int)h) << 16);
}
__device__ __forceinline__ float dot4(float4 a, float4 b) {
    return a.x*b.x + a.y*b.y + a.z*b.z + a.w*b.w;
}

// ---------------- Kernel A: fused projections f,g,h ----------------
// Khi/Klo[b][i][64], Qhi/Qlo[b][i][64] (bf16 hi/lo split), Vt[b][d][4096] (bf16)
__global__ __launch_bounds__(256) void proj_kernel(
    const float* __restrict__ x, const float* __restrict__ Wf,
    const float* __restrict__ Wg, const float* __restrict__ Wh,
    unsigned short* __restrict__ Khi, unsigned short* __restrict__ Klo,
    unsigned short* __restrict__ Qhi, unsigned short* __restrict__ Qlo,
    unsigned short* __restrict__ Vt)
{
    __shared__ float xs[64][PAD];    // [ii][cc] then reused as transpose stage
    __shared__ float ws[192][PAD];   // [m*64+o][cc]
    const int t  = threadIdx.x;
    const int b  = blockIdx.x >> 6;
    const int i0 = (blockIdx.x & 63) << 6;
    const int oq = t >> 4;
    const int iq = t & 15;

    float acc[3][4][4];
    #pragma unroll
    for (int m = 0; m < 3; m++)
        #pragma unroll
        for (int a = 0; a < 4; a++)
            #pragma unroll
            for (int e = 0; e < 4; e++) acc[m][a][e] = 0.f;

    for (int c0 = 0; c0 < CC; c0 += 64) {
        __syncthreads();
        #pragma unroll
        for (int rep = 0; rep < 4; rep++) {
            int lin = rep*1024 + t*4;
            int cc = lin >> 6, ii = lin & 63;
            float4 v = *(const float4*)(x + ((size_t)(b*CC + c0 + cc))*NN + i0 + ii);
            xs[ii+0][cc] = v.x; xs[ii+1][cc] = v.y; xs[ii+2][cc] = v.z; xs[ii+3][cc] = v.w;
        }
        #pragma unroll
        for (int rep = 0; rep < 12; rep++) {
            int lin = rep*1024 + t*4;
            int row = lin >> 6, cc = lin & 63;
            const float* wp = (row < 64) ? Wf : ((row < 128) ? Wg : Wh);
            int o = row & 63;
            *(float4*)&ws[row][cc] = *(const float4*)(wp + (size_t)o*CC + c0 + cc);
        }
        __syncthreads();
        #pragma unroll
        for (int m = 0; m < 3; m++) {
            #pragma unroll
            for (int c4 = 0; c4 < 16; c4++) {
                float4 w[4], xv[4];
                #pragma unroll
                for (int oo = 0; oo < 4; oo++)
                    w[oo] = *(const float4*)&ws[m*64 + oq + 16*oo][c4*4];
                #pragma unroll
                for (int e = 0; e < 4; e++)
                    xv[e] = *(const float4*)&xs[iq + 16*e][c4*4];
                #pragma unroll
                for (int oo = 0; oo < 4; oo++)
                    #pragma unroll
                    for (int e = 0; e < 4; e++)
                        acc[m][oo][e] += dot4(w[oo], xv[e]);
            }
        }
    }

    // ---- Epilogue: LDS transpose + bf16 stores ----
    const int r  = t >> 2;         // output row within tile
    const int c  = (t & 3) * 16;   // 16-col chunk

    // K (m=0) and Q (m=1): stage [i][d], store hi/lo rows [b][i][64]
    #pragma unroll
    for (int m = 0; m < 2; m++) {
        __syncthreads();
        #pragma unroll
        for (int oo = 0; oo < 4; oo++)
            #pragma unroll
            for (int e = 0; e < 4; e++)
                xs[iq + 16*e][oq + 16*oo] = acc[m][oo][e];
        __syncthreads();
        us8 hv[2], lv[2];
        #pragma unroll
        for (int q = 0; q < 2; q++)
            #pragma unroll
            for (int k = 0; k < 8; k++) {
                float v = xs[r][c + q*8 + k];
                unsigned short hb = f2bf(v);
                hv[q][k] = hb;
                lv[q][k] = f2bf(v - bf2f(hb));
            }
        size_t off = ((size_t)b*NN + i0 + r)*64 + c;
        unsigned short* Hp = (m == 0) ? Khi : Qhi;
        unsigned short* Lp = (m == 0) ? Klo : Qlo;
        *(us8*)(Hp + off)     = hv[0];
        *(us8*)(Hp + off + 8) = hv[1];
        *(us8*)(Lp + off)     = lv[0];
        *(us8*)(Lp + off + 8) = lv[1];
    }

    // V (m=2): stage transposed [d][i], store bf16 rows of Vt[b][d][4096]
    __syncthreads();
    #pragma unroll
    for (int oo = 0; oo < 4; oo++)
        #pragma unroll
        for (int e = 0; e < 4; e++)
            xs[oq + 16*oo][iq + 16*e] = acc[2][oo][e];
    __syncthreads();
    {
        us8 vv[2];
        #pragma unroll
        for (int q = 0; q < 2; q++)
            #pragma unroll
            for (int k = 0; k < 8; k++)
                vv[q][k] = f2bf(xs[r][c + q*8 + k]);
        size_t off = ((size_t)b*64 + r)*NN + i0 + c;
        *(us8*)(Vt + off)     = vv[0];
        *(us8*)(Vt + off + 8) = vv[1];
    }
}

// ---------------- Kernel B: MFMA flash attention, barrier-free ----------------
// saT[b][j][d] = sum_i softmax_i(Q[j]·K[i]) * V[i][d]  (no-max softmax)
__global__ __launch_bounds__(256, 1) void attn_kernel(
    const unsigned short* __restrict__ Khi, const unsigned short* __restrict__ Klo,
    const unsigned short* __restrict__ Qhi, const unsigned short* __restrict__ Qlo,
    const unsigned short* __restrict__ Vt,  float* __restrict__ saT)
{
    __shared__ float Ps[4][16][PAD];   // per-wave private P tile [j_local][i]
    const int t    = threadIdx.x;
    const int wv   = t >> 6;
    const int lane = t & 63;
    const int lh   = lane & 15;   // "outer" frag index
    const int qd   = lane >> 4;   // quad
    const int b    = blockIdx.x >> 6;
    const int j0   = ((blockIdx.x & 63) << 6) + wv*16;  // this wave's 16 query rows

    // Q A-frags (resident whole kernel): lane reads Q[j0+lh][qd*8 + 32*ks ..+8]
    const size_t qb = ((size_t)b*NN + j0 + lh)*64 + qd*8;
    short8 qhi[2], qlo[2];
    qhi[0] = *(const short8*)(Qhi + qb);
    qhi[1] = *(const short8*)(Qhi + qb + 32);
    qlo[0] = *(const short8*)(Qlo + qb);
    qlo[1] = *(const short8*)(Qlo + qb + 32);

    f32x4 o_acc[4];
    float l_r[4];
    #pragma unroll
    for (int dt = 0; dt < 4; dt++) { o_acc[dt][0]=0.f; o_acc[dt][1]=0.f; o_acc[dt][2]=0.f; o_acc[dt][3]=0.f; }
    #pragma unroll
    for (int r = 0; r < 4; r++) l_r[r] = 0.f;

    const size_t kroot = ((size_t)b*NN + lh)*64 + qd*8;   // + kt*4096 + it*1024 + ks*32
    const size_t vroot = ((size_t)b*64 + lh)*NN + qd*8;   // + kt*64 + dt*65536 + ks*32

#define LOADKV(KH, KL, VF, kt) do {                                          \
    size_t kb_ = kroot + (size_t)(kt)*4096;                                  \
    size_t vb_ = vroot + (size_t)(kt)*64;                                    \
    _Pragma("unroll")                                                        \
    for (int it_ = 0; it_ < 4; it_++) {                                      \
        _Pragma("unroll")                                                    \
        for (int ks_ = 0; ks_ < 2; ks_++) {                                  \
            KH[it_][ks_] = *(const short8*)(Khi + kb_ + it_*1024 + ks_*32);  \
            KL[it_][ks_] = *(const short8*)(Klo + kb_ + it_*1024 + ks_*32);  \
        } }                                                                  \
    _Pragma("unroll")                                                        \
    for (int dt_ = 0; dt_ < 4; dt_++) {                                      \
        _Pragma("unroll")                                                    \
        for (int ks_ = 0; ks_ < 2; ks_++)                                    \
            VF[dt_][ks_] = *(const short8*)(Vt + vb_ + dt_*65536 + ks_*32);  \
    } } while (0)

#define COMPUTE(KH, KL, VF) do {                                             \
    f32x4 s_[4];                                                             \
    _Pragma("unroll")                                                        \
    for (int it_ = 0; it_ < 4; it_++) {                                      \
        s_[it_][0]=0.f; s_[it_][1]=0.f; s_[it_][2]=0.f; s_[it_][3]=0.f;      \
        s_[it_] = __builtin_amdgcn_mfma_f32_16x16x32_bf16(qhi[0], KH[it_][0], s_[it_], 0,0,0); \
        s_[it_] = __builtin_amdgcn_mfma_f32_16x16x32_bf16(qhi[1], KH[it_][1], s_[it_], 0,0,0); \
        s_[it_] = __builtin_amdgcn_mfma_f32_16x16x32_bf16(qhi[0], KL[it_][0], s_[it_], 0,0,0); \
        s_[it_] = __builtin_amdgcn_mfma_f32_16x16x32_bf16(qhi[1], KL[it_][1], s_[it_], 0,0,0); \
        s_[it_] = __builtin_amdgcn_mfma_f32_16x16x32_bf16(qlo[0], KH[it_][0], s_[it_], 0,0,0); \
        s_[it_] = __builtin_amdgcn_mfma_f32_16x16x32_bf16(qlo[1], KH[it_][1], s_[it_], 0,0,0); \
    }                                                                        \
    _Pragma("unroll")                                                        \
    for (int it_ = 0; it_ < 4; it_++)                                        \
        _Pragma("unroll")                                                    \
        for (int r_ = 0; r_ < 4; r_++) {                                     \
            float p_ = __expf(s_[it_][r_]);                                  \
            l_r[r_] += p_;                                                   \
            Ps[wv][qd*4 + r_][it_*16 + lh] = p_;                             \
        }                                                                    \
    asm volatile("s_waitcnt lgkmcnt(0)" ::: "memory");                       \
    short8 pf_[2];                                                           \
    _Pragma("unroll")                                                        \
    for (int ks_ = 0; ks_ < 2; ks_++) {                                      \
        const float* pp_ = &Ps[wv][lh][ks_*32 + qd*8];                       \
        f32x4 x0_ = *(const f32x4*)pp_;                                      \
        f32x4 x1_ = *(const f32x4*)(pp_ + 4);                                \
        pf_[ks_][0] = (short)f2bf(x0_[0]); pf_[ks_][1] = (short)f2bf(x0_[1]);\
        pf_[ks_][2] = (short)f2bf(x0_[2]); pf_[ks_][3] = (short)f2bf(x0_[3]);\
        pf_[ks_][4] = (short)f2bf(x1_[0]); pf_[ks_][5] = (short)f2bf(x1_[1]);\
        pf_[ks_][6] = (short)f2bf(x1_[2]); pf_[ks_][7] = (short)f2bf(x1_[3]);\
    }                                                                        \
    _Pragma("unroll")                                                        \
    for (int dt_ = 0; dt_ < 4; dt_++) {                                      \
        o_acc[dt_] = __builtin_amdgcn_mfma_f32_16x16x32_bf16(pf_[0], VF[dt_][0], o_acc[dt_], 0,0,0); \
        o_acc[dt_] = __builtin_amdgcn_mfma_f32_16x16x32_bf16(pf_[1], VF[dt_][1], o_acc[dt_], 0,0,0); \
    } } while (0)

    short8 khiA[4][2], kloA[4][2], vfA[4][2];
    short8 khiB[4][2], kloB[4][2], vfB[4][2];
    LOADKV(khiA, kloA, vfA, 0);
    for (int kt = 0; kt < 64; kt += 2) {
        LOADKV(khiB, kloB, vfB, kt + 1);
        COMPUTE(khiA, kloA, vfA);
        if (kt + 2 < 64) LOADKV(khiA, kloA, vfA, kt + 2);
        COMPUTE(khiB, kloB, vfB);
    }
#undef LOADKV
#undef COMPUTE

    // reduce l over the 16 lanes holding the same j rows (bits 0..3 of lane)
    #pragma unroll
    for (int r = 0; r < 4; r++) {
        float l = l_r[r];
        #pragma unroll
        for (int off = 1; off < 16; off <<= 1)
            l += __shfl_xor(l, off);
        l_r[r] = 1.0f / l;
    }
    #pragma unroll
    for (int dt = 0; dt < 4; dt++)
        #pragma unroll
        for (int r = 0; r < 4; r++)
            saT[((size_t)b*NN + j0 + qd*4 + r)*64 + dt*16 + lh] = o_acc[dt][r] * l_r[r];
}

// ---------------- Kernel C: output projection + residual ----------------
__global__ __launch_bounds__(256) void outproj_kernel(
    const float* __restrict__ saT, const float* __restrict__ Wv,
    const float* __restrict__ x, const float* __restrict__ gamma,
    float* __restrict__ out1, float* __restrict__ out2)
{
    __shared__ float sas[64][PAD];
    __shared__ float wvs[64][PAD];
    const int t  = threadIdx.x;
    const int b  = blockIdx.x >> 6;
    const int j0 = (blockIdx.x & 63) << 6;
    const int oq = t >> 4;
    const int jq = t & 15;
    const float g = gamma[0];

    #pragma unroll
    for (int rep = 0; rep < 4; rep++) {
        int lin = rep*1024 + t*4;
        int jj = lin >> 6, d = lin & 63;
        *(float4*)&sas[jj][d] = *(const float4*)(saT + ((size_t)b*NN + j0 + jj)*64 + d);
    }

    for (int oc = 0; oc < 8; oc++) {
        __syncthreads();
        #pragma unroll
        for (int rep = 0; rep < 4; rep++) {
            int lin = rep*1024 + t*4;
            int oo = lin >> 6, d = lin & 63;
            *(float4*)&wvs[oo][d] = *(const float4*)(Wv + (size_t)(oc*64 + oo)*64 + d);
        }
        __syncthreads();

        float acc[4][4];
        #pragma unroll
        for (int a = 0; a < 4; a++)
            #pragma unroll
            for (int e = 0; e < 4; e++) acc[a][e] = 0.f;

        #pragma unroll 4
        for (int d4 = 0; d4 < 16; d4++) {
            float4 w[4], sv[4];
            #pragma unroll
            for (int oo = 0; oo < 4; oo++)
                w[oo] = *(const float4*)&wvs[oq + 16*oo][d4*4];
            #pragma unroll
            for (int jj = 0; jj < 4; jj++)
                sv[jj] = *(const float4*)&sas[jq + 16*jj][d4*4];
            #pragma unroll
            for (int oo = 0; oo < 4; oo++)
                #pragma unroll
                for (int jj = 0; jj < 4; jj++)
                    acc[oo][jj] += dot4(w[oo], sv[jj]);
        }

        #pragma unroll
        for (int oo = 0; oo < 4; oo++) {
            int o = oc*64 + oq + 16*oo;
            #pragma unroll
            for (int jj = 0; jj < 4; jj++) {
                size_t idx = ((size_t)(b*CC + o))*NN + j0 + jq + 16*jj;
                float sv = acc[oo][jj];
                out2[idx] = sv;
                out1[idx] = g*sv + x[idx];
            }
        }
    }
}

extern "C" void kernel_launch(void* const* d_in, const int* in_sizes, int n_in,
                              void* d_out, int out_size, void* d_ws, size_t ws_size,
                              hipStream_t stream) {
    const float* x     = (const float*)d_in[0];
    const float* Wf    = (const float*)d_in[1];
    const float* Wg    = (const float*)d_in[2];
    const float* Wh    = (const float*)d_in[3];
    const float* Wv    = (const float*)d_in[4];
    const float* gamma = (const float*)d_in[5];

    float* out1 = (float*)d_out;
    float* out2 = out1 + (size_t)BB*CC*NN;

    const size_t BND = (size_t)BB*NN*64;   // 1M elements
    char* w = (char*)d_ws;
    unsigned short* Khi = (unsigned short*)w;            w += BND*2;
    unsigned short* Klo = (unsigned short*)w;            w += BND*2;
    unsigned short* Qhi = (unsigned short*)w;            w += BND*2;
    unsigned short* Qlo = (unsigned short*)w;            w += BND*2;
    unsigned short* Vt  = (unsigned short*)w;            w += BND*2;
    float*          saT = (float*)w;

    dim3 grid(BB*64), block(256);
    proj_kernel<<<grid, block, 0, stream>>>(x, Wf, Wg, Wh, Khi, Klo, Qhi, Qlo, Vt);
    attn_kernel<<<grid, block, 0, stream>>>(Khi, Klo, Qhi, Qlo, Vt, saT);
    outproj_kernel<<<grid, block, 0, stream>>>(saT, Wv, x, gamma, out1, out2);
}

// Round 3
// 245.013 us; speedup vs baseline: 2.7642x; 1.8475x over previous
//
#include <hip/hip_runtime.h>
#include <cstddef>

#define BB 4
#define CC 512
#define NN 4096

using half8  = __attribute__((ext_vector_type(8))) _Float16;
using short8 = __attribute__((ext_vector_type(8))) short;
using f32x4  = __attribute__((ext_vector_type(4))) float;

__device__ __forceinline__ unsigned short f2bf(float x) {
    unsigned int u = __float_as_uint(x);
    u += 0x7fffu + ((u >> 16) & 1u);
    return (unsigned short)(u >> 16);
}

// ---------------- Kernel 0: weight conversion to fp16 ----------------
// Wc16 [192][512] = cat(Wf,Wg,Wh); Wv16 [512][64]
__global__ __launch_bounds__(256) void prep_kernel(
    const float* __restrict__ Wf, const float* __restrict__ Wg,
    const float* __restrict__ Wh, const float* __restrict__ Wv,
    _Float16* __restrict__ Wc16, _Float16* __restrict__ Wv16)
{
    int idx = blockIdx.x * 256 + threadIdx.x;
    int stride = gridDim.x * 256;
    const int N1 = 192 * 512, N2 = 512 * 64;
    for (int i = idx; i < N1 + N2; i += stride) {
        if (i < N1) {
            int row = i >> 9, c = i & 511;
            const float* src = (row < 64) ? Wf : ((row < 128) ? Wg : Wh);
            Wc16[i] = (_Float16)src[(row & 63) * 512 + c];
        } else {
            int k = i - N1;
            Wv16[k] = (_Float16)Wv[k];
        }
    }
}

// ---------------- Kernel 1: fused projections f,g,h via fp16 MFMA ----------------
// Kf[b][i][64] (=f), Qf[b][i][64] (=g) fp16;  Vt[b][d][4096] (=h) bf16
__global__ __launch_bounds__(256) void proj_kernel(
    const float* __restrict__ x, const _Float16* __restrict__ Wc16,
    _Float16* __restrict__ Kf, _Float16* __restrict__ Qf,
    unsigned short* __restrict__ Vt)
{
    const int t    = threadIdx.x;
    const int w    = t >> 6;
    const int lane = t & 63;
    const int lh   = lane & 15;
    const int qd   = lane >> 4;
    const int b    = blockIdx.x >> 6;
    const int i0   = (blockIdx.x & 63) << 6;

    f32x4 acc[3][4];
    #pragma unroll
    for (int ot = 0; ot < 3; ot++)
        #pragma unroll
        for (int it = 0; it < 4; it++) { acc[ot][it][0]=0.f; acc[ot][it][1]=0.f; acc[ot][it][2]=0.f; acc[ot][it][3]=0.f; }

    const float* xb = x + (size_t)b*CC*NN + i0;
    const _Float16* wb = Wc16 + (size_t)(w*48 + lh)*512 + qd*8;

    for (int ck = 0; ck < 16; ck++) {
        // x B-frags: lane holds x^T[i = i0+it*16+lh][c = ck*32+qd*8 .. +8]
        half8 xf[4];
        #pragma unroll
        for (int it = 0; it < 4; it++) {
            const float* xp = xb + (size_t)(ck*32 + qd*8)*NN + it*16 + lh;
            #pragma unroll
            for (int jj = 0; jj < 8; jj++)
                xf[it][jj] = (_Float16)xp[(size_t)jj * NN];
        }
        #pragma unroll
        for (int ot = 0; ot < 3; ot++) {
            half8 wf = *(const half8*)(wb + (size_t)(ot*16)*512 + ck*32);
            #pragma unroll
            for (int it = 0; it < 4; it++)
                acc[ot][it] = __builtin_amdgcn_mfma_f32_16x16x32_f16(wf, xf[it], acc[ot][it], 0, 0, 0);
        }
    }

    // epilogue: D element (o_tile g16 = w*3+ot; o_loc = (g16&3)*16 + qd*4 + r; i = i0+it*16+lh)
    #pragma unroll
    for (int ot = 0; ot < 3; ot++) {
        int g16 = w*3 + ot;
        int m   = g16 >> 2;
        int obase = (g16 & 3)*16 + qd*4;
        #pragma unroll
        for (int it = 0; it < 4; it++) {
            int ig = i0 + it*16 + lh;
            #pragma unroll
            for (int r = 0; r < 4; r++) {
                float v = acc[ot][it][r];
                int ol = obase + r;
                if (m == 0)       Kf[((size_t)b*NN + ig)*64 + ol] = (_Float16)v;
                else if (m == 1)  Qf[((size_t)b*NN + ig)*64 + ol] = (_Float16)v;
                else              Vt[((size_t)b*64 + ol)*NN + ig] = f2bf(v);
            }
        }
    }
}

// ---------------- Kernel 2: MFMA flash attention (softmax over keys i) ----------------
// sa16[b][j][d] fp16 = sum_i softmax_i(Q[j]·K[i]) * V[i][d]   (no-max softmax)
__global__ __launch_bounds__(256, 1) void attn_kernel(
    const _Float16* __restrict__ Kf, const _Float16* __restrict__ Qf,
    const unsigned short* __restrict__ Vt, _Float16* __restrict__ sa16)
{
    __shared__ float Ps[4][16][68];   // per-wave private P tile [j_local][i]
    const int t    = threadIdx.x;
    const int wv   = t >> 6;
    const int lane = t & 63;
    const int lh   = lane & 15;
    const int qd   = lane >> 4;

    // XCD-aware swizzle: batch b pinned to XCDs {2b,2b+1} -> K/V working set fits per-XCD L2
    const int B   = blockIdx.x;
    const int xcd = B & 7;
    const int rr  = B >> 3;
    const int b   = xcd >> 1;
    const int jt  = rr*2 + (xcd & 1);
    const int j0  = (jt << 6) + wv*16;

    const size_t qb = ((size_t)b*NN + j0 + lh)*64 + qd*8;
    half8 qf[2];
    qf[0] = *(const half8*)(Qf + qb);
    qf[1] = *(const half8*)(Qf + qb + 32);

    f32x4 o_acc[4];
    float l_r[4];
    #pragma unroll
    for (int dt = 0; dt < 4; dt++) { o_acc[dt][0]=0.f; o_acc[dt][1]=0.f; o_acc[dt][2]=0.f; o_acc[dt][3]=0.f; }
    #pragma unroll
    for (int r = 0; r < 4; r++) l_r[r] = 0.f;

    const size_t kroot = ((size_t)b*NN + lh)*64 + qd*8;   // + kt*4096 + it*1024 + ks*32
    const size_t vroot = ((size_t)b*64 + lh)*NN + qd*8;   // + kt*64 + dt*65536 + ks*32

#define LOADKV(KF, VF, kt) do {                                              \
    size_t kb_ = kroot + (size_t)(kt)*4096;                                  \
    size_t vb_ = vroot + (size_t)(kt)*64;                                    \
    _Pragma("unroll")                                                        \
    for (int it_ = 0; it_ < 4; it_++) {                                      \
        _Pragma("unroll")                                                    \
        for (int ks_ = 0; ks_ < 2; ks_++)                                    \
            KF[it_][ks_] = *(const half8*)(Kf + kb_ + it_*1024 + ks_*32);    \
    }                                                                        \
    _Pragma("unroll")                                                        \
    for (int dt_ = 0; dt_ < 4; dt_++) {                                      \
        _Pragma("unroll")                                                    \
        for (int ks_ = 0; ks_ < 2; ks_++)                                    \
            VF[dt_][ks_] = *(const short8*)(Vt + vb_ + dt_*65536 + ks_*32);  \
    } } while (0)

#define COMPUTE(KF, VF) do {                                                 \
    f32x4 s_[4];                                                             \
    _Pragma("unroll")                                                        \
    for (int it_ = 0; it_ < 4; it_++) {                                      \
        s_[it_][0]=0.f; s_[it_][1]=0.f; s_[it_][2]=0.f; s_[it_][3]=0.f;      \
        s_[it_] = __builtin_amdgcn_mfma_f32_16x16x32_f16(qf[0], KF[it_][0], s_[it_], 0,0,0); \
        s_[it_] = __builtin_amdgcn_mfma_f32_16x16x32_f16(qf[1], KF[it_][1], s_[it_], 0,0,0); \
    }                                                                        \
    _Pragma("unroll")                                                        \
    for (int it_ = 0; it_ < 4; it_++)                                        \
        _Pragma("unroll")                                                    \
        for (int r_ = 0; r_ < 4; r_++) {                                     \
            float p_ = __expf(s_[it_][r_]);                                  \
            l_r[r_] += p_;                                                   \
            Ps[wv][qd*4 + r_][it_*16 + lh] = p_;                             \
        }                                                                    \
    asm volatile("s_waitcnt lgkmcnt(0)" ::: "memory");                       \
    short8 pf_[2];                                                           \
    _Pragma("unroll")                                                        \
    for (int ks_ = 0; ks_ < 2; ks_++) {                                      \
        const float* pp_ = &Ps[wv][lh][ks_*32 + qd*8];                       \
        f32x4 x0_ = *(const f32x4*)pp_;                                      \
        f32x4 x1_ = *(const f32x4*)(pp_ + 4);                                \
        pf_[ks_][0] = (short)f2bf(x0_[0]); pf_[ks_][1] = (short)f2bf(x0_[1]);\
        pf_[ks_][2] = (short)f2bf(x0_[2]); pf_[ks_][3] = (short)f2bf(x0_[3]);\
        pf_[ks_][4] = (short)f2bf(x1_[0]); pf_[ks_][5] = (short)f2bf(x1_[1]);\
        pf_[ks_][6] = (short)f2bf(x1_[2]); pf_[ks_][7] = (short)f2bf(x1_[3]);\
    }                                                                        \
    _Pragma("unroll")                                                        \
    for (int dt_ = 0; dt_ < 4; dt_++) {                                      \
        o_acc[dt_] = __builtin_amdgcn_mfma_f32_16x16x32_bf16(pf_[0], VF[dt_][0], o_acc[dt_], 0,0,0); \
        o_acc[dt_] = __builtin_amdgcn_mfma_f32_16x16x32_bf16(pf_[1], VF[dt_][1], o_acc[dt_], 0,0,0); \
    } } while (0)

    half8  kfA[4][2], kfB[4][2];
    short8 vfA[4][2], vfB[4][2];
    LOADKV(kfA, vfA, 0);
    for (int kt = 0; kt < 64; kt += 2) {
        LOADKV(kfB, vfB, kt + 1);
        COMPUTE(kfA, vfA);
        if (kt + 2 < 64) LOADKV(kfA, vfA, kt + 2);
        COMPUTE(kfB, vfB);
    }
#undef LOADKV
#undef COMPUTE

    // reduce l over the 16 lh-lanes sharing each j-row
    #pragma unroll
    for (int r = 0; r < 4; r++) {
        float l = l_r[r];
        #pragma unroll
        for (int off = 1; off < 16; off <<= 1)
            l += __shfl_xor(l, off);
        l_r[r] = 1.0f / l;
    }
    #pragma unroll
    for (int dt = 0; dt < 4; dt++)
        #pragma unroll
        for (int r = 0; r < 4; r++)
            sa16[((size_t)b*NN + j0 + qd*4 + r)*64 + dt*16 + lh] = (_Float16)(o_acc[dt][r] * l_r[r]);
}

// ---------------- Kernel 3: output projection + residual via fp16 MFMA ----------------
// out2[b][o][j] = sum_d Wv[o][d] sa[j][d];  out1 = gamma*out2 + x
__global__ __launch_bounds__(256) void outproj_kernel(
    const _Float16* __restrict__ sa16, const _Float16* __restrict__ Wv16,
    const float* __restrict__ x, const float* __restrict__ gamma,
    float* __restrict__ out1, float* __restrict__ out2)
{
    const int t    = threadIdx.x;
    const int w    = t >> 6;
    const int lane = t & 63;
    const int lh   = lane & 15;
    const int qd   = lane >> 4;
    const int b    = blockIdx.x >> 6;
    const int j0   = (blockIdx.x & 63) << 6;
    const float g  = gamma[0];

    // persistent B-frags: sa[j = j0+jt*16+lh][d]
    half8 sb[4][2];
    #pragma unroll
    for (int jt2 = 0; jt2 < 4; jt2++) {
        const size_t sbase = ((size_t)b*NN + j0 + jt2*16 + lh)*64 + qd*8;
        sb[jt2][0] = *(const half8*)(sa16 + sbase);
        sb[jt2][1] = *(const half8*)(sa16 + sbase + 32);
    }

    #pragma unroll 2
    for (int ot8 = 0; ot8 < 8; ot8++) {
        const int ot = w*8 + ot8;
        const size_t wbase = (size_t)(ot*16 + lh)*64 + qd*8;
        half8 a0 = *(const half8*)(Wv16 + wbase);
        half8 a1 = *(const half8*)(Wv16 + wbase + 32);
        #pragma unroll
        for (int jt2 = 0; jt2 < 4; jt2++) {
            f32x4 acc; acc[0]=0.f; acc[1]=0.f; acc[2]=0.f; acc[3]=0.f;
            acc = __builtin_amdgcn_mfma_f32_16x16x32_f16(a0, sb[jt2][0], acc, 0, 0, 0);
            acc = __builtin_amdgcn_mfma_f32_16x16x32_f16(a1, sb[jt2][1], acc, 0, 0, 0);
            const int jg = j0 + jt2*16 + lh;
            #pragma unroll
            for (int r = 0; r < 4; r++) {
                const int o = ot*16 + qd*4 + r;
                size_t idx = ((size_t)b*CC + o)*NN + jg;
                float v = acc[r];
                out2[idx] = v;
                out1[idx] = fmaf(g, v, x[idx]);
            }
        }
    }
}

extern "C" void kernel_launch(void* const* d_in, const int* in_sizes, int n_in,
                              void* d_out, int out_size, void* d_ws, size_t ws_size,
                              hipStream_t stream) {
    const float* x     = (const float*)d_in[0];
    const float* Wf    = (const float*)d_in[1];
    const float* Wg    = (const float*)d_in[2];
    const float* Wh    = (const float*)d_in[3];
    const float* Wv    = (const float*)d_in[4];
    const float* gamma = (const float*)d_in[5];

    float* out1 = (float*)d_out;
    float* out2 = out1 + (size_t)BB*CC*NN;

    const size_t BND = (size_t)BB*NN*64;   // 1M elements
    char* wp = (char*)d_ws;
    _Float16*       Kf   = (_Float16*)wp;        wp += BND*2;
    _Float16*       Qf   = (_Float16*)wp;        wp += BND*2;
    unsigned short* Vt   = (unsigned short*)wp;  wp += BND*2;
    _Float16*       sa16 = (_Float16*)wp;        wp += BND*2;
    _Float16*       Wc16 = (_Float16*)wp;        wp += (size_t)192*512*2;
    _Float16*       Wv16 = (_Float16*)wp;

    prep_kernel<<<dim3(64), dim3(256), 0, stream>>>(Wf, Wg, Wh, Wv, Wc16, Wv16);
    proj_kernel<<<dim3(BB*64), dim3(256), 0, stream>>>(x, Wc16, Kf, Qf, Vt);
    attn_kernel<<<dim3(BB*64), dim3(256), 0, stream>>>(Kf, Qf, Vt, sa16);
    outproj_kernel<<<dim3(BB*64), dim3(256), 0, stream>>>(sa16, Wv16, x, gamma, out1, out2);
}